// Round 6
// baseline (55.830 us; speedup 1.0000x reference)
//
#include <hip/hip_runtime.h>
#include <stdint.h>

// Reference: pos += fl32(vel*dt); vel += fl32(fl32(-9.81)*fl32(0.01)); record pos.
// r6: vel is independent of pos and exactly piecewise-linear (one constant f32
// increment per binade, since vel stays on its ulp grid -> identical rounding
// every step). Phase 1 computes the EXACT scan vel staircase from n=0 (~60
// segments, ballot-verified). Rows n<NS use the exact-vel integral (error =
// scan's pos-cell rounding sawtooth only, <=~3.5e7). Rows n>=NS use pos
// run-events anchored with EXACT vel (kills r5's DeltaV*dt*(N-ns)=2.7e8 error
// mechanism); events ~90 -> ~15 since run length ~ n^2.

static constexpr long long NSTEPS = 10000000LL;  // output rows
static constexpr long long NS     = 4000000LL;   // model/event cutover (even)
static constexpr int SEGCAP0 = 1024;
static constexpr int RUNCAP0 = 2048;
static constexpr int SEG_LDS = 320;
static constexpr int RUN_LDS = 320;

__device__ __forceinline__ bool same_binade_f32(float a, float b) {
    return (((__float_as_uint(a) ^ __float_as_uint(b)) & 0xFF800000u) == 0u);
}

__global__ __launch_bounds__(64) void prepass(
        const float* __restrict__ pos0, const float* __restrict__ vel0,
        int* __restrict__ counts,
        int* __restrict__ g_segm, double* __restrict__ g_segV,
        double* __restrict__ g_segc, double* __restrict__ g_segP,
        int* __restrict__ g_rn0, double* __restrict__ g_rpos,
        double* __restrict__ g_rinc, int segcap, int runcap)
{
    __shared__ int    s_m[SEGCAP0 + 1];
    __shared__ double s_c[SEGCAP0];
    const int lane = threadIdx.x;
    const float dtf  = 0.01f;
    const float gdtf = __fmul_rn(-9.81f, dtf);
    const double dtd = (double)dtf;

    // ---- Phase 1: exact velocity staircase from n=0 (vel independent of pos).
    double V = (double)vel0[1];
    double P = (double)pos0[1];   // model pos prefix: p0 + dt*sum(vel_k, k<m)
    long long m = 0;
    int nseg = 0;
    double aP = 0.0, aV = 0.0; int aj = 0; bool have_anchor = false;

    while (m < NSTEPS && nseg < segcap) {
        const float vf  = (float)V;                    // exact (V on f32 grid)
        const float vn1 = __fadd_rn(vf, gdtf);
        const double c  = (double)vn1 - V;             // exact f32 increment
        const long long rem = NSTEPS - m;

        long long Lb = rem;
        const float cf = (float)c;
        if (vf == 0.0f) {
            Lb = 64;                                   // no bound near zero; split
        } else if (cf != 0.0f) {
            int k; (void)frexpf(vf, &k);               // |vf| in [2^(k-1), 2^k)
            float s = vf < 0.0f ? -1.0f : 1.0f;
            float B = ((vf < 0.0f) == (cf < 0.0f)) ? ldexpf(s, k) : ldexpf(s, k - 1);
            float r = __fdividef(B - vf, cf);          // exact numerator (same binade)
            if (r >= 0.0f && r < 4.0e9f) Lb = (long long)r + 1;
        }
        long long Lhi = Lb + 2;
        if (Lhi > rem) Lhi = rem;
        if (Lhi < 1) Lhi = 1;

        long long L = 1, base = Lhi;
        for (int round = 0; round < 32; ++round) {
            const long long candL = base - 63 + (long long)lane;
            bool valid = false;
            if (candL >= 1) {
                const double ve = V + (double)(candL - 1) * c;  // exact dyadics
                const float vef = (float)ve;
                const float vn2 = __fadd_rn(vef, gdtf);
                valid = ((double)vef == ve)                 // representable
                     && same_binade_f32(vef, vf)            // rounding regime fixed
                     && ((double)vn2 - ve == c);            // endpoint increment
            }
            unsigned long long msk = __ballot(valid);
            if (msk) { L = base - 63 + (long long)(63 - __clzll(msk)); break; }
            base -= 64;
            if (base < 1) break;                        // L=1 fallback (always valid)
        }
        if (L < 1) L = 1;
        if (L > rem) L = rem;

        if (lane == 0) {
            s_m[nseg] = (int)m; s_c[nseg] = c;
            g_segm[nseg] = (int)m; g_segV[nseg] = V; g_segc[nseg] = c; g_segP[nseg] = P;
        }
        if (!have_anchor && NS >= m && NS < m + L) {    // exact state at NS
            const double t = (double)(NS - m);
            aV = V + t * c;
            aP = P + dtd * (t * V + c * (t * (t - 1.0) * 0.5));
            aj = nseg;
            have_anchor = true;
        }
        ++nseg;
        P += dtd * ((double)L * V + c * ((double)L * (double)(L - 1) * 0.5));
        V += (double)L * c;
        m += L;
    }
    if (lane == 0) { s_m[nseg] = 0x7fffffff; g_segm[nseg] = 0x7fffffff; counts[0] = nseg; }
    if (!have_anchor) { aV = V; aP = P; aj = nseg > 0 ? nseg - 1 : 0; }  // unreachable guard
    __syncthreads();

    // ---- Phase 2: pos run-events from NS, with EXACT vel (cv from seg table).
    double pos = (double)(float)aP;                    // snap model pos to f32 grid
    double vel = aV;                                   // exact scan vel at NS
    long long n = NS;
    int jj = aj, nrun = 0;
    while (n < NSTEPS - 1 && nrun < runcap) {
        while (s_m[jj + 1] <= (int)n) ++jj;            // sentinel INT_MAX stops
        const double cv = s_c[jj];
        long long Lcap = (long long)s_m[jj + 1] - n;   // cv valid for these steps
        const long long rem = (NSTEPS - 1) - n;
        if (Lcap > rem) Lcap = rem;

        const float pf = (float)pos;                   // exact (pos on f32 grid)
        const float vf2 = (float)vel;
        const float dstep = __fmul_rn(vf2, dtf);
        const float pn1 = __fadd_rn(pf, dstep);
        const double inc = (double)pn1 - pos;          // exact f32 pos increment

        long long La = Lcap, Lc = Lcap;
        const float incf = (float)inc;
        if (pf == 0.0f) {
            La = 64;
        } else if (incf != 0.0f) {                     // pos binade exit
            int k; (void)frexpf(pf, &k);
            float s = pf < 0.0f ? -1.0f : 1.0f;
            float B = ((pf < 0.0f) == (incf < 0.0f)) ? ldexpf(s, k) : ldexpf(s, k - 1);
            float r = __fdividef(B - pf, incf);
            if (r >= 0.0f && r < 4.0e9f) { La = (long long)r - 1; if (La < 0) La = 0; }
        }
        const double dd = cv * dtd;
        if (dd != 0.0 && pf != 0.0f) {                 // pos-increment cell crossing
            int k; (void)frexpf(pf, &k);
            const float ulpf = ldexpf(1.0f, k - 24);
            const double d0 = (double)dstep;
            const double T = inc + (dd < 0.0 ? -0.5 : 0.5) * (double)ulpf;
            float r = __fdividef((float)(T - d0), (float)dd);
            if (r >= 0.0f && r < 4.0e9f) { Lc = (long long)r + 2; if (Lc < 1) Lc = 1; }
        }
        long long Lhi = La < Lc ? La : Lc;
        Lhi += 3;
        if (Lhi > Lcap) Lhi = Lcap;
        if (Lhi < 1) Lhi = 1;

        long long L = 1, base = Lhi;
        for (int round = 0; round < 32; ++round) {
            const long long candL = base - 63 + (long long)lane;
            bool valid = false;
            if (candL >= 1) {
                const double pe = pos + (double)(candL - 1) * inc;  // exact dyadics
                const double ve = vel + (double)(candL - 1) * cv;
                const float pef = (float)pe;
                const float vef = (float)ve;
                const float d2  = __fmul_rn(vef, dtf);
                const float pn2 = __fadd_rn(pef, d2);
                valid = ((double)pef == pe)
                     && same_binade_f32(pef, pf)
                     && ((double)vef == ve)
                     && ((double)pn2 - pe == inc);
            }
            unsigned long long msk = __ballot(valid);
            if (msk) { L = base - 63 + (long long)(63 - __clzll(msk)); break; }
            base -= 64;
            if (base < 1) break;
        }
        if (L < 1) L = 1;
        if (L > rem) L = rem;

        if (lane == 0) { g_rn0[nrun] = (int)n; g_rpos[nrun] = pos; g_rinc[nrun] = inc; }
        ++nrun;
        pos += (double)L * inc;                        // exact: grid-aligned dyadics
        vel += (double)L * cv;
        n += L;
    }
    if (lane == 0) counts[1] = nrun;
}

__global__ __launch_bounds__(256) void fill(
        const float* __restrict__ pos0, const float* __restrict__ vel0,
        const int* __restrict__ counts,
        const int* __restrict__ g_segm, const double* __restrict__ g_segV,
        const double* __restrict__ g_segc, const double* __restrict__ g_segP,
        const int* __restrict__ g_rn0, const double* __restrict__ g_rpos,
        const double* __restrict__ g_rinc,
        float4* __restrict__ out, long long npairs)
{
    __shared__ int    t_sm[SEG_LDS + 1];
    __shared__ double t_sV[SEG_LDS], t_sc[SEG_LDS], t_sP[SEG_LDS];
    __shared__ int    t_rn[RUN_LDS];
    __shared__ double t_rp[RUN_LDS], t_ri[RUN_LDS];

    const float dtf = 0.01f;
    const double dtd = (double)dtf;
    const double p0x = (double)pos0[0];
    const double cx  = (double)__fmul_rn(vel0[0], dtf);  // constant f32 x-increment

    const int nseg = counts[0];
    const int nrun = counts[1];
    const bool segL = (nseg > 0 && nseg <= SEG_LDS);
    const bool runL = (nrun > 0 && nrun <= RUN_LDS);
    if (segL) for (int i = threadIdx.x; i <= nseg; i += blockDim.x) {
        t_sm[i] = g_segm[i];
        if (i < nseg) { t_sV[i] = g_segV[i]; t_sc[i] = g_segc[i]; t_sP[i] = g_segP[i]; }
    }
    if (runL) for (int i = threadIdx.x; i < nrun; i += blockDim.x) {
        t_rn[i] = g_rn0[i]; t_rp[i] = g_rpos[i]; t_ri[i] = g_rinc[i];
    }
    __syncthreads();

    const int*    pm = segL ? (const int*)t_sm    : g_segm;
    const double* pV = segL ? (const double*)t_sV : g_segV;
    const double* pc = segL ? (const double*)t_sc : g_segc;
    const double* pP = segL ? (const double*)t_sP : g_segP;
    const int*    rn = runL ? (const int*)t_rn    : g_rn0;
    const double* rp = runL ? (const double*)t_rp : g_rpos;
    const double* ri = runL ? (const double*)t_ri : g_rinc;

    const long long stride = (long long)gridDim.x * blockDim.x;
    for (long long i = (long long)blockIdx.x * blockDim.x + threadIdx.x;
         i < npairs; i += stride) {
        const long long m0 = 2 * i, m1 = m0 + 1;
        float4 o;
        o.x = (float)(p0x + (double)m0 * cx);
        o.z = (float)(p0x + (double)m1 * cx);

        if (m1 < NS) {  // exact-vel integral model (NS even => pair same side)
            const int t0 = (int)m0;
            int lo = 0, hi = nseg - 1;
            while (lo < hi) { int mid = (lo + hi + 1) >> 1; if (pm[mid] <= t0) lo = mid; else hi = mid - 1; }
            double t = (double)(m0 - pm[lo]);
            o.y = (float)(pP[lo] + dtd * (t * pV[lo] + pc[lo] * (t * (t - 1.0) * 0.5)));
            const int j1 = (pm[lo + 1] <= (int)m1) ? lo + 1 : lo;
            t = (double)(m1 - pm[j1]);
            o.w = (float)(pP[j1] + dtd * (t * pV[j1] + pc[j1] * (t * (t - 1.0) * 0.5)));
        } else {        // run-event region
            const int t0 = (int)m0;
            int lo = 0, hi = nrun - 1;
            while (lo < hi) { int mid = (lo + hi + 1) >> 1; if (rn[mid] <= t0) lo = mid; else hi = mid - 1; }
            o.y = (float)(rp[lo] + (double)(m0 - rn[lo]) * ri[lo]);
            const int j1 = (lo + 1 < nrun && rn[lo + 1] <= (int)m1) ? lo + 1 : lo;
            o.w = (float)(rp[j1] + (double)(m1 - rn[j1]) * ri[j1]);
        }
        out[i] = o;
    }
}

extern "C" void kernel_launch(void* const* d_in, const int* in_sizes, int n_in,
                              void* d_out, int out_size, void* d_ws, size_t ws_size,
                              hipStream_t stream) {
    // Inputs: [0] ball_mass (unused), [1] initial_position[2], [2] initial_velocity[2].
    const float* pos0 = (const float*)d_in[1];
    const float* vel0 = (const float*)d_in[2];

    int segcap = SEGCAP0, runcap = RUNCAP0;
    auto need = [](int sc, int rc) -> size_t {
        size_t off = 64;
        off += ((size_t)(sc + 1) * 4 + 7) & ~(size_t)7;
        off += (size_t)sc * 8 * 3;
        off += ((size_t)rc * 4 + 7) & ~(size_t)7;
        off += (size_t)rc * 8 * 2;
        return off;
    };
    while (need(segcap, runcap) > ws_size && segcap > 64) { segcap >>= 1; runcap >>= 1; }

    char* base = (char*)d_ws;
    size_t off = 64;
    int* counts = (int*)base;
    int* g_segm = (int*)(base + off);
    off += ((size_t)(segcap + 1) * 4 + 7) & ~(size_t)7;
    double* g_segV = (double*)(base + off); off += (size_t)segcap * 8;
    double* g_segc = (double*)(base + off); off += (size_t)segcap * 8;
    double* g_segP = (double*)(base + off); off += (size_t)segcap * 8;
    int* g_rn0 = (int*)(base + off);
    off += ((size_t)runcap * 4 + 7) & ~(size_t)7;
    double* g_rpos = (double*)(base + off); off += (size_t)runcap * 8;
    double* g_rinc = (double*)(base + off);

    prepass<<<1, 64, 0, stream>>>(pos0, vel0, counts,
                                  g_segm, g_segV, g_segc, g_segP,
                                  g_rn0, g_rpos, g_rinc, segcap, runcap);

    const long long npairs = (long long)out_size / 4;  // 5,000,000 float4s
    fill<<<2048, 256, 0, stream>>>(pos0, vel0, counts,
                                   g_segm, g_segV, g_segc, g_segP,
                                   g_rn0, g_rpos, g_rinc,
                                   (float4*)d_out, npairs);
}